// Round 7
// baseline (11830.493 us; speedup 1.0000x reference)
//
#include <hip/hip_runtime.h>
#include <stdint.h>

// Problem constants (fixed by reference setup_inputs())
#define NVARS  50000
#define NLIT   100000      // 2*NVARS
#define NCLS   200000
#define NNODE  300000      // NLIT + NCLS
#define NEDGE  800000
#define DD     128
#define NROUNDS 16
#define NSEG   300000      // NCLS clause segments + NLIT literal segments
#define CSRN   1600000     // 2*NEDGE

typedef __attribute__((ext_vector_type(8))) short   short8;
typedef __attribute__((ext_vector_type(4))) float   floatx4;

typedef __attribute__((address_space(1))) const void gvoid_t;
typedef __attribute__((address_space(3))) void       svoid_t;

static __device__ __forceinline__ float bf2f(uint16_t u){
  union { uint32_t i; float f; } v; v.i = ((uint32_t)u) << 16; return v.f;
}
static __device__ __forceinline__ uint16_t f2bf(float f){
  union { float f; uint32_t i; } v; v.f = f;
  uint32_t x = v.i;
  return (uint16_t)((x + 0x7fffu + ((x >> 16) & 1u)) >> 16);   // RNE
}
static __device__ __forceinline__ float sane(float x){ return (fabsf(x) < 1e30f) ? x : 0.0f; }
static __device__ __forceinline__ float sigm(float x){ return 1.0f / (1.0f + __expf(-x)); }
static __device__ __forceinline__ float tanh_f(float x){ return 1.0f - 2.0f / (__expf(2.0f*x) + 1.0f); }

// ---------------- init: h = broadcast init vectors (bf16), c = 0 (fp32) -----
__global__ void k_init(const float* __restrict__ Lw, const float* __restrict__ Lb,
                       const float* __restrict__ Cw, const float* __restrict__ Cb,
                       uint16_t* __restrict__ hb, float* __restrict__ c32){
  long tid = (long)blockIdx.x*256 + threadIdx.x;
  if (tid >= (long)NNODE*DD) return;
  int d = (int)(tid & (DD-1));
  long i = tid >> 7;
  float v = (i < NLIT) ? (Lw[d] + Lb[d]) : (Cw[d] + Cb[d]);
  hb[tid] = f2bf(v);
  c32[tid] = 0.0f;
}

// ---------------- setup: LSTM weights fp32->bf16 concat + fp32 bias sums ----
__global__ void k_setup(const float* __restrict__ Cu_wih, const float* __restrict__ Cu_whh,
                        const float* __restrict__ Cu_bih, const float* __restrict__ Cu_bhh,
                        const float* __restrict__ Lu_wih, const float* __restrict__ Lu_whh,
                        const float* __restrict__ Lu_bih, const float* __restrict__ Lu_bhh,
                        uint16_t* __restrict__ Wc, uint16_t* __restrict__ Wl,
                        float* __restrict__ bsc, float* __restrict__ bsl){
  int n = blockIdx.x;          // 0..511 (gate-major row, torch order i|f|g|o)
  int t = threadIdx.x;         // 0..127
  Wc[n*256 + t]       = f2bf(Cu_wih[n*128 + t]);
  Wc[n*256 + 128 + t] = f2bf(Cu_whh[n*128 + t]);
  Wl[n*384 + t]       = f2bf(Lu_wih[n*256 + t]);
  Wl[n*384 + 128 + t] = f2bf(Lu_wih[n*256 + 128 + t]);
  Wl[n*384 + 256 + t] = f2bf(Lu_whh[n*128 + t]);
  if (t == 0){
    bsc[n] = Cu_bih[n] + Cu_bhh[n];
    bsl[n] = Lu_bih[n] + Lu_bhh[n];
  }
}

// ---------------- MLP weights fp32 -> bf16 ----------------------------------
__global__ void k_cvtmsg(const float* __restrict__ LmW, const float* __restrict__ CmW,
                         uint16_t* __restrict__ LmWb, uint16_t* __restrict__ CmWb){
  int i = blockIdx.x*256 + threadIdx.x;       // 0 .. 2*49152
  if (i < 49152)            LmWb[i]         = f2bf(LmW[i]);
  else if (i < 2*49152)     CmWb[i - 49152] = f2bf(CmW[i - 49152]);
}

// ---------------- CSR build (both directions, one unified segment array) ----
__global__ void k_hist(const int* esrc, const int* edst, int* cnt){
  int e = blockIdx.x*256 + threadIdx.x; if (e >= NEDGE) return;
  int s = esrc[e], d = edst[e];
  if ((unsigned)d < (unsigned)NCLS) atomicAdd(&cnt[d], 1);
  if ((unsigned)s < (unsigned)NLIT) atomicAdd(&cnt[NCLS + s], 1);
}

__global__ void k_reduce(const int* cnt, int* part){
  __shared__ int sm[1024];
  int i = blockIdx.x*1024 + threadIdx.x;
  sm[threadIdx.x] = (i < NSEG) ? cnt[i] : 0;
  __syncthreads();
  for (int s = 512; s > 0; s >>= 1){
    if (threadIdx.x < s) sm[threadIdx.x] += sm[threadIdx.x + s];
    __syncthreads();
  }
  if (threadIdx.x == 0) part[blockIdx.x] = sm[0];
}

__global__ void k_scanpart(int* part, int nb){
  if (blockIdx.x == 0 && threadIdx.x == 0){
    int s = 0;
    for (int b = 0; b < nb; ++b){ int v = part[b]; part[b] = s; s += v; }
  }
}

__global__ void k_scanapply(const int* cnt, const int* part, int* off, int* cur){
  __shared__ int sm[1024];
  int i = blockIdx.x*1024 + threadIdx.x;
  int v = (i < NSEG) ? cnt[i] : 0;
  sm[threadIdx.x] = v;
  __syncthreads();
  for (int s = 1; s < 1024; s <<= 1){
    int t = (threadIdx.x >= s) ? sm[threadIdx.x - s] : 0;
    __syncthreads();
    sm[threadIdx.x] += t;
    __syncthreads();
  }
  if (i < NSEG){
    int excl = part[blockIdx.x] + sm[threadIdx.x] - v;
    off[i] = excl; cur[i] = excl;
    if (i == NSEG-1) off[NSEG] = excl + v;
  }
}

__global__ void k_scatter(const int* esrc, const int* edst, int* cur, int* csr){
  int e = blockIdx.x*256 + threadIdx.x; if (e >= NEDGE) return;
  int s = esrc[e], d = edst[e];
  if ((unsigned)s < (unsigned)NLIT && (unsigned)d < (unsigned)NCLS){
    int p  = atomicAdd(&cur[d], 1);        if ((unsigned)p  < (unsigned)CSRN) csr[p]  = s;
    int p2 = atomicAdd(&cur[NCLS + s], 1); if ((unsigned)p2 < (unsigned)CSRN) csr[p2] = d;
  }
}

// ---------------- segment sum: one wave per segment row (bf16 internal) -----
__global__ void k_segsum(const uint16_t* __restrict__ rows, int rowsN,
                         uint16_t* __restrict__ out,
                         const int* __restrict__ off, const int* __restrict__ csr,
                         int nseg, int segbase){
  int seg = blockIdx.x*4 + (threadIdx.x >> 6);
  if (seg >= nseg) return;
  int lane = threadIdx.x & 63;
  int s0 = off[segbase + seg], s1 = off[segbase + seg + 1];
  if (s0 < 0) s0 = 0;
  if (s1 > CSRN) s1 = CSRN;
  float ax = 0.f, ay = 0.f;
  for (int e = s0; e < s1; ++e){
    unsigned idx = (unsigned)csr[e];
    if (idx >= (unsigned)rowsN) idx = 0;     // defensive: wrong-but-finite
    uint32_t v = *reinterpret_cast<const uint32_t*>(rows + (size_t)idx*DD + lane*2);
    ax += bf2f((uint16_t)(v & 0xffffu));
    ay += bf2f((uint16_t)(v >> 16));
  }
  ax = sane(ax); ay = sane(ay);
  *reinterpret_cast<uint32_t*>(out + (size_t)seg*DD + lane*2) =
      (uint32_t)f2bf(ax) | ((uint32_t)f2bf(ay) << 16);
}

// ---------------- fused 3-layer MLP: out = L3(relu(L2(relu(L1(A))))) --------
// (unchanged from round 6 — verified WIN)
__global__ void __launch_bounds__(512, 4)
k_mlp3(const uint16_t* __restrict__ A, const uint16_t* __restrict__ W,
       const float* __restrict__ bias, uint16_t* __restrict__ out, int M){
  __shared__ uint16_t sX[8192];   // 16 KB: layer input
  __shared__ uint16_t sY[8192];   // 16 KB: layer output
  int tid  = threadIdx.x;
  int wv   = tid >> 6, lane = tid & 63;
  int mrow = lane & 15, qq = lane >> 4;
  int r0   = blockIdx.x*64;
  int slot = qq ^ ((mrow >> 1) & 3);     // swizzled read slot
  int j    = wv*16 + mrow;               // this thread's out-col (all layers)

  short8 bfr[3][4];
#pragma unroll
  for (int l = 0; l < 3; ++l)
#pragma unroll
    for (int kt = 0; kt < 4; ++kt)
      bfr[l][kt] = *reinterpret_cast<const short8*>(
          W + (size_t)l*16384 + (size_t)j*DD + kt*32 + qq*8);

#pragma unroll
  for (int p = 0; p < 2; ++p){
    int chunk = p*512 + tid;
    int kt  = chunk >> 8;
    int row = (chunk >> 2) & 63;
    int c   = chunk & 3;
    int qc  = c ^ ((row >> 1) & 3);
    long r  = r0 + row; if (r > M-1) r = M-1;        // tail clamp
    const uint16_t* src = A + (size_t)r*DD + kt*32 + qc*8;
    __builtin_amdgcn_global_load_lds((gvoid_t*)src,
                                     (svoid_t*)&sX[(size_t)(p*512 + wv*64)*8],
                                     16, 0, 0);
  }

  int ktj = j >> 5;                      // out-col's kstep (as next-layer k)
  int qcj = (j >> 3) & 3;                // out-col's chunk within kstep
  __syncthreads();                       // staging complete (vmcnt drained)

  uint16_t* sIn  = sX;
  uint16_t* sOut = sY;
#pragma unroll
  for (int l = 0; l < 3; ++l){
    float bv = bias[l*128 + j];
    floatx4 acc[4];
#pragma unroll
    for (int mi = 0; mi < 4; ++mi){ floatx4 z = {0.f,0.f,0.f,0.f}; acc[mi] = z; }
#pragma unroll
    for (int kt = 0; kt < 4; ++kt)
#pragma unroll
      for (int mi = 0; mi < 4; ++mi){
        short8 af = *reinterpret_cast<const short8*>(
            &sIn[(size_t)((kt*64 + mi*16 + mrow)*4 + slot)*8]);
        acc[mi] = __builtin_amdgcn_mfma_f32_16x16x32_bf16(af, bfr[l][kt], acc[mi], 0, 0, 0);
      }
    if (l < 2){
#pragma unroll
      for (int mi = 0; mi < 4; ++mi)
#pragma unroll
        for (int r2 = 0; r2 < 4; ++r2){
          int row = mi*16 + qq*4 + r2;
          float v = sane(acc[mi][r2] + bv);
          v = v > 0.f ? v : 0.f;                     // relu between layers
          int s = qcj ^ ((row >> 1) & 3);
          sOut[(size_t)((ktj*64 + row)*4 + s)*8 + (j & 7)] = f2bf(v);
        }
      __syncthreads();                   // sOut ready; sIn fully consumed
      uint16_t* t = sIn; sIn = sOut; sOut = t;
    } else {
#pragma unroll
      for (int mi = 0; mi < 4; ++mi)
#pragma unroll
        for (int r2 = 0; r2 < 4; ++r2){
          int row = r0 + mi*16 + qq*4 + r2;
          float v = sane(acc[mi][r2] + bv);
          if (row < M) out[(size_t)row*DD + j] = f2bf(v);
        }
    }
  }
}

// ---------------- clause LSTM v6: register-resident B, no LDS ---------------
// Block = 512 thr (8 waves) x 64 rows; wave fb owns feature cols [fb*16,+16)
// x 4 gates. The wave's FULL W-panel (4 gates x 8 K-steps = 32 short8 =
// 128 VGPR) is hoisted to registers in a prologue: W read exactly once per
// block (zero intra-block redundancy), L2-resident across blocks. K-loop =
// 4 A-loads (own rows, L1/L2-hot; 8x wave fan-out absorbed by cache) + 16
// reg-MFMA per step - no LDS, no in-loop barriers, so the compiler can
// pipeline A-loads arbitrarily deep (v4's failure was B in-loop: 16
// dependent loads/step with no spare VGPRs; B is now hoisted).
// __launch_bounds__(512,2): VGPR cap 256 (128 B + 64 acc + ~40 addr/pipe).
// A0 = c_msg, A1 = LIVE hbC (own rows only). __syncthreads() before the
// epilogue: all waves' A-reads retired before any wave writes its col-slice
// (waves read ALL cols of block rows but write disjoint 16-col slices).
// Numerics identical: same fragments, same K accumulation order (region 0
// k0..127 then region 1 k0..127).
__global__ void __launch_bounds__(512, 2)
k_lstm_cls(const uint16_t* __restrict__ A0, const uint16_t* __restrict__ A1,
           const uint16_t* __restrict__ W, const float* __restrict__ bias,
           float* __restrict__ c32, uint16_t* __restrict__ hout, int M){
  int tid  = threadIdx.x;
  int wv   = tid >> 6, lane = tid & 63;
  int mrow = lane & 15, qq = lane >> 4;
  int fb   = wv;
  int r0   = blockIdx.x*64;                    // 3125*64 = 200000 exact

  // B prologue: wave's whole W-panel -> regs (32 x 16B, W read once/block)
  short8 breg[4][8];
#pragma unroll
  for (int gg = 0; gg < 4; ++gg)
#pragma unroll
    for (int t = 0; t < 8; ++t)
      breg[gg][t] = *reinterpret_cast<const short8*>(
          W + (size_t)(gg*128 + fb*16 + mrow)*256 + t*32 + qq*8);

  const uint16_t* ap[2][4];
#pragma unroll
  for (int mi = 0; mi < 4; ++mi){
    int r = r0 + mi*16 + mrow; if (r > M-1) r = M-1;
    ap[0][mi] = A0 + (size_t)r*DD + qq*8;
    ap[1][mi] = A1 + (size_t)r*DD + qq*8;
  }

  floatx4 acc[4][4];                           // [mi][gg]
#pragma unroll
  for (int i = 0; i < 4; ++i)
#pragma unroll
    for (int j2 = 0; j2 < 4; ++j2){ floatx4 z = {0.f,0.f,0.f,0.f}; acc[i][j2] = z; }

#pragma unroll
  for (int t = 0; t < 8; ++t){
    const int rg = t >> 2, ko = (t & 3)*32;
    short8 af[4];
#pragma unroll
    for (int mi = 0; mi < 4; ++mi)
      af[mi] = *reinterpret_cast<const short8*>(ap[rg][mi] + ko);
#pragma unroll
    for (int mi = 0; mi < 4; ++mi)
#pragma unroll
      for (int gg = 0; gg < 4; ++gg)
        acc[mi][gg] = __builtin_amdgcn_mfma_f32_16x16x32_bf16(af[mi], breg[gg][t], acc[mi][gg], 0, 0, 0);
  }

  __syncthreads();   // live-hbC: all waves' A reads retired before any write

  int j = fb*16 + mrow;
  float bi = bias[j], bfv = bias[j+128], bg = bias[j+256], bo = bias[j+384];
#pragma unroll
  for (int mi = 0; mi < 4; ++mi){
    floatx4 vi = acc[mi][0], vf = acc[mi][1], vg = acc[mi][2], vo = acc[mi][3];
#pragma unroll
    for (int r2 = 0; r2 < 4; ++r2){
      int row = r0 + mi*16 + qq*4 + r2;
      if (row < M){
        size_t ix = (size_t)row*DD + j;
        float iv = sane(vi[r2] + bi);
        float fv = sane(vf[r2] + bfv);
        float gv = sane(vg[r2] + bg);
        float ov = sane(vo[r2] + bo);
        float c0 = sane(c32[ix]);
        float c2 = sigm(fv)*c0 + sigm(iv)*tanh_f(gv);
        c32[ix]  = c2;
        hout[ix] = f2bf(sigm(ov)*tanh_f(c2));
      }
    }
  }
}

// ---------------- literal LSTM v6: v5b LDS pipeline + PAIRED rows -----------
// Block covers rows {b*32..+31} U {NVARS+b*32..+31} (local row lr 0..63;
// gr = lr<32 ? b*32+lr : NVARS+b*32+lr-32). Negation of lr = (lr+32)&63 is
// BLOCK-LOCAL -> A1 (negated h) and A2 (own h) read LIVE hb safely: v5b's
// loop-final vmcnt(0)+s_barrier retires all A reads before any epilogue
// write. This deletes the literal snapshot (k_copy16) entirely.
// Same v5b W/A LDS double-buffer, XOR swizzle, counted-vmcnt sync.
// Numerics identical (snapshot == live for all rows read; block grouping
// doesn't affect row-wise math).
__global__ void __launch_bounds__(512, 4)
k_lstm_lit(const uint16_t* __restrict__ A0, const uint16_t* __restrict__ hbl,
           const uint16_t* __restrict__ W, const float* __restrict__ bias,
           float* __restrict__ c32, uint16_t* __restrict__ hout){
  constexpr int NT = 12;                       // K=384
  __shared__ uint16_t sW[2][16384];            // [512 gate-rows][32 k], 64 KB
  __shared__ uint16_t sA[2][2048];             // [64 rows][32 k], 8 KB

  int tid  = threadIdx.x;
  int wv   = tid >> 6, lane = tid & 63;
  int mrow = lane & 15, qq = lane >> 4;
  int fb   = wv;
  long base = (long)blockIdx.x*32;
  int wvu  = __builtin_amdgcn_readfirstlane(wv);

  int slot = qq ^ ((mrow >> 1) & 3);           // swizzled read slot
  int sq   = (lane & 3) ^ ((lane >> 3) & 3);   // staging content chunk
  int srow = wv*16 + (lane >> 2);              // W stage row (mod 128)
  int alr  = (wv & 3)*16 + (lane >> 2);        // A stage local row (wv<4)

  // paired local row -> global literal row (clamped; writes guarded)
  auto pmap = [&](int lr)->long {
    long g = (lr < 32) ? base + lr : (long)NVARS + base + (lr - 32);
    long cap = (lr < 32) ? (long)NVARS - 1 : (long)NLIT - 1;
    return g > cap ? cap : g;
  };

  floatx4 acc[4][4];                           // [mi][gg]
#pragma unroll
  for (int i = 0; i < 4; ++i)
#pragma unroll
    for (int j2 = 0; j2 < 4; ++j2){ floatx4 z = {0.f,0.f,0.f,0.f}; acc[i][j2] = z; }

  auto stage = [&](int buf, int tn){
    int kt = tn*32;
#pragma unroll
    for (int c = 0; c < 4; ++c){
      const uint16_t* src = W + (size_t)(srow + c*128)*384 + kt + sq*8;
      __builtin_amdgcn_global_load_lds((gvoid_t*)src,
                                       (svoid_t*)&sW[buf][wv*512 + c*4096],
                                       16, 0, 0);
    }
    if (wvu < 4){
      int rg = tn >> 2;                        // 0 = l_msg, 1 = neg h, 2 = own h
      int lr = (rg == 1) ? ((alr + 32) & 63) : alr;
      long gr = pmap(lr);
      const uint16_t* Ar = (rg == 0) ? A0 : hbl;
      const uint16_t* asrc = Ar + (size_t)gr*DD + (tn & 3)*32 + sq*8;
      __builtin_amdgcn_global_load_lds((gvoid_t*)asrc,
                                       (svoid_t*)&sA[buf][wv*512],
                                       16, 0, 0);
    }
  };

  stage(0, 0);
  asm volatile("s_waitcnt vmcnt(0)" ::: "memory");
  __builtin_amdgcn_sched_barrier(0);
  __builtin_amdgcn_s_barrier();
  __builtin_amdgcn_sched_barrier(0);

#pragma unroll
  for (int t = 0; t < NT; ++t){
    const int cur = t & 1;
    if (t + 1 < NT){
      stage(cur ^ 1, t + 1);                   // prefetch stays in flight
      if (wvu < 4) asm volatile("s_waitcnt vmcnt(5)" ::: "memory");
      else         asm volatile("s_waitcnt vmcnt(4)" ::: "memory");
    } else {
      asm volatile("s_waitcnt vmcnt(0)" ::: "memory");
    }
    __builtin_amdgcn_sched_barrier(0);
    __builtin_amdgcn_s_barrier();              // all waves' stage(t) retired
    __builtin_amdgcn_sched_barrier(0);

    short8 af[4], bf[4];
#pragma unroll
    for (int mi = 0; mi < 4; ++mi)
      af[mi] = *reinterpret_cast<const short8*>(&sA[cur][(mi*16 + mrow)*32 + slot*8]);
#pragma unroll
    for (int gg = 0; gg < 4; ++gg)
      bf[gg] = *reinterpret_cast<const short8*>(&sW[cur][(gg*128 + fb*16 + mrow)*32 + slot*8]);
#pragma unroll
    for (int mi = 0; mi < 4; ++mi)
#pragma unroll
      for (int gg = 0; gg < 4; ++gg)
        acc[mi][gg] = __builtin_amdgcn_mfma_f32_16x16x32_bf16(af[mi], bf[gg], acc[mi][gg], 0, 0, 0);

    asm volatile("s_waitcnt lgkmcnt(0)" ::: "memory");
    __builtin_amdgcn_sched_barrier(0);
    __builtin_amdgcn_s_barrier();              // reads done before buf reuse
    __builtin_amdgcn_sched_barrier(0);
  }

  int j = fb*16 + mrow;
  float bi = bias[j], bfv = bias[j+128], bg = bias[j+256], bo = bias[j+384];
#pragma unroll
  for (int mi = 0; mi < 4; ++mi){
    floatx4 vi = acc[mi][0], vf = acc[mi][1], vg = acc[mi][2], vo = acc[mi][3];
#pragma unroll
    for (int r2 = 0; r2 < 4; ++r2){
      int lrow = mi*16 + qq*4 + r2;            // local row 0..63
      bool valid = (lrow < 32) ? (base + lrow < NVARS)
                               : (base + (lrow - 32) < NVARS);
      if (valid){
        long grow = (lrow < 32) ? base + lrow : (long)NVARS + base + (lrow - 32);
        size_t ix = (size_t)grow*DD + j;
        float iv = sane(vi[r2] + bi);
        float fv = sane(vf[r2] + bfv);
        float gv = sane(vg[r2] + bg);
        float ov = sane(vo[r2] + bo);
        float c0 = sane(c32[ix]);
        float c2 = sigm(fv)*c0 + sigm(iv)*tanh_f(gv);
        c32[ix]  = c2;
        hout[ix] = f2bf(sigm(ov)*tanh_f(c2));
      }
    }
  }
}

// ---------------- finalize: hb (bf16) -> d_out (fp32), overwrites c32 -------
__global__ void k_final(const uint16_t* __restrict__ hb, float* __restrict__ out){
  long i = (long)blockIdx.x*256 + threadIdx.x;   // units of 4 elements
  if (i >= (long)NNODE*DD/4) return;
  ushort4 v = *reinterpret_cast<const ushort4*>(hb + i*4);
  float4 o;
  o.x = bf2f(v.x); o.y = bf2f(v.y); o.z = bf2f(v.z); o.w = bf2f(v.w);
  *reinterpret_cast<float4*>(out + i*4) = o;
}

// ---------------------------------------------------------------------------
extern "C" void kernel_launch(void* const* d_in, const int* in_sizes, int n_in,
                              void* d_out, int out_size, void* d_ws, size_t ws_size,
                              hipStream_t stream){
  // FP32 float inputs (per reference: jax.random.normal -> float32)
  const float* Lw     = (const float*)d_in[0];
  const float* Lb     = (const float*)d_in[1];
  const float* Cw     = (const float*)d_in[2];
  const float* Cb     = (const float*)d_in[3];
  const float* LmW    = (const float*)d_in[4];    // [3,128,128]
  const float* LmB    = (const float*)d_in[5];    // [3,128] -> used directly as bias
  const float* CmW    = (const float*)d_in[6];
  const float* CmB    = (const float*)d_in[7];
  const float* Cu_wih = (const float*)d_in[8];    // [512,128]
  const float* Cu_whh = (const float*)d_in[9];
  const float* Cu_bih = (const float*)d_in[10];
  const float* Cu_bhh = (const float*)d_in[11];
  const float* Lu_wih = (const float*)d_in[12];   // [512,256]
  const float* Lu_whh = (const float*)d_in[13];   // [512,128]
  const float* Lu_bih = (const float*)d_in[14];
  const float* Lu_bhh = (const float*)d_in[15];
  const int* esrc = (const int*)d_in[16];
  const int* edst = (const int*)d_in[17];
  // d_in[18..20]: n_vars / n_clauses / num_rounds — fixed, hardcoded.

  // Workspace carve-up (~191 MB). fp32 c-state lives in d_out (153.6 MB),
  // which is dead scratch until k_final overwrites it with fp32 h.
  char* p = (char*)d_ws;
  auto alloc = [&](size_t bytes)->char* {
    char* r = p; p += (bytes + 255) & ~(size_t)255; return r;
  };
  int* cnt  = (int*)alloc((size_t)NSEG*4);
  int* off  = (int*)alloc((size_t)(NSEG+1)*4);
  int* cur  = (int*)alloc((size_t)NSEG*4);
  int nb = (NSEG + 1023) / 1024;                       // 293
  int* part = (int*)alloc((size_t)nb*4);
  int* csr  = (int*)alloc((size_t)CSRN*4);
  uint16_t* Wc   = (uint16_t*)alloc((size_t)512*256*2);
  uint16_t* Wl   = (uint16_t*)alloc((size_t)512*384*2);
  uint16_t* LmWb = (uint16_t*)alloc((size_t)3*128*128*2);
  uint16_t* CmWb = (uint16_t*)alloc((size_t)3*128*128*2);
  float* bsc = (float*)alloc(512*4);
  float* bsl = (float*)alloc(512*4);
  uint16_t* t0 = (uint16_t*)alloc((size_t)NCLS*DD*2);   // 51.2 MB
  uint16_t* t1 = (uint16_t*)alloc((size_t)NCLS*DD*2);   // 51.2 MB
  uint16_t* hb = (uint16_t*)alloc((size_t)NNODE*DD*2);  // 76.8 MB

  float* c32 = (float*)d_out;                    // fp32 c-state scratch in d_out
  uint16_t* hbC = hb  + (size_t)NLIT*DD;
  float*    cL  = c32;
  float*    cC  = c32 + (size_t)NLIT*DD;

  // ---- setup phase (ws re-poisoned every call: rebuild everything) ----
  hipMemsetAsync(cnt, 0, (size_t)NSEG*4, stream);
  k_init<<<(NNODE*DD + 255)/256, 256, 0, stream>>>(Lw, Lb, Cw, Cb, hb, c32);
  k_setup<<<512, 128, 0, stream>>>(Cu_wih, Cu_whh, Cu_bih, Cu_bhh,
                                   Lu_wih, Lu_whh, Lu_bih, Lu_bhh,
                                   Wc, Wl, bsc, bsl);
  k_cvtmsg<<<(2*49152 + 255)/256, 256, 0, stream>>>(LmW, CmW, LmWb, CmWb);
  k_hist<<<(NEDGE + 255)/256, 256, 0, stream>>>(esrc, edst, cnt);
  k_reduce<<<nb, 1024, 0, stream>>>(cnt, part);
  k_scanpart<<<1, 64, 0, stream>>>(part, nb);
  k_scanapply<<<nb, 1024, 0, stream>>>(cnt, part, off, cur);
  k_scatter<<<(NEDGE + 255)/256, 256, 0, stream>>>(esrc, edst, cur, csr);

  for (int rd = 0; rd < NROUNDS; ++rd){
    // literal message MLP (fused 3 layers): hb[0:NLIT] -> t0 (= lm)
    k_mlp3<<<1563, 512, 0, stream>>>(hb, LmWb, LmB, t0, NLIT);
    // clause inbox: c_msg[c] = sum lm[src]  -> t1
    k_segsum<<<50000, 256, 0, stream>>>(t0, NLIT, t1, off, csr, NCLS, 0);
    // clause LSTM (reg-B): A=[c_msg | live hbC], writes hbC,cC
    k_lstm_cls<<<3125, 512, 0, stream>>>(t1, hbC, Wc, bsc, cC, hbC, NCLS);
    // clause message MLP (fused 3 layers): hbC -> t0 (= cm)
    k_mlp3<<<3125, 512, 0, stream>>>(hbC, CmWb, CmB, t0, NCLS);
    // literal inbox: l_msg[l] = sum cm[dst]  -> t1
    k_segsum<<<25000, 256, 0, stream>>>(t0, NCLS, t1, off, csr, NLIT, NCLS);
    // literal LSTM (paired rows, live hb, no snapshot): writes hb,cL
    k_lstm_lit<<<1563, 512, 0, stream>>>(t1, hb, Wl, bsl, cL, hb);
  }

  // final: convert bf16 h -> fp32 output (c-state in d_out is dead now)
  k_final<<<(NNODE*DD/4 + 255)/256, 256, 0, stream>>>(hb, (float*)d_out);
}

// Round 8
// 9338.049 us; speedup vs baseline: 1.2669x; 1.2669x over previous
//
#include <hip/hip_runtime.h>
#include <stdint.h>

// Problem constants (fixed by reference setup_inputs())
#define NVARS  50000
#define NLIT   100000      // 2*NVARS
#define NCLS   200000
#define NNODE  300000      // NLIT + NCLS
#define NEDGE  800000
#define DD     128
#define NROUNDS 16
#define NSEG   300000      // NCLS clause segments + NLIT literal segments
#define CSRN   1600000     // 2*NEDGE

typedef __attribute__((ext_vector_type(8))) short   short8;
typedef __attribute__((ext_vector_type(4))) float   floatx4;

typedef __attribute__((address_space(1))) const void gvoid_t;
typedef __attribute__((address_space(3))) void       svoid_t;

static __device__ __forceinline__ float bf2f(uint16_t u){
  union { uint32_t i; float f; } v; v.i = ((uint32_t)u) << 16; return v.f;
}
static __device__ __forceinline__ uint16_t f2bf(float f){
  union { float f; uint32_t i; } v; v.f = f;
  uint32_t x = v.i;
  return (uint16_t)((x + 0x7fffu + ((x >> 16) & 1u)) >> 16);   // RNE
}
static __device__ __forceinline__ float sane(float x){ return (fabsf(x) < 1e30f) ? x : 0.0f; }
static __device__ __forceinline__ float sigm(float x){ return 1.0f / (1.0f + __expf(-x)); }
static __device__ __forceinline__ float tanh_f(float x){ return 1.0f - 2.0f / (__expf(2.0f*x) + 1.0f); }

// ---------------- init: h = broadcast init vectors (bf16), c = 0 (fp32) -----
__global__ void k_init(const float* __restrict__ Lw, const float* __restrict__ Lb,
                       const float* __restrict__ Cw, const float* __restrict__ Cb,
                       uint16_t* __restrict__ hb, float* __restrict__ c32){
  long tid = (long)blockIdx.x*256 + threadIdx.x;
  if (tid >= (long)NNODE*DD) return;
  int d = (int)(tid & (DD-1));
  long i = tid >> 7;
  float v = (i < NLIT) ? (Lw[d] + Lb[d]) : (Cw[d] + Cb[d]);
  hb[tid] = f2bf(v);
  c32[tid] = 0.0f;
}

// ---------------- setup: LSTM weights fp32->bf16 concat + fp32 bias sums ----
__global__ void k_setup(const float* __restrict__ Cu_wih, const float* __restrict__ Cu_whh,
                        const float* __restrict__ Cu_bih, const float* __restrict__ Cu_bhh,
                        const float* __restrict__ Lu_wih, const float* __restrict__ Lu_whh,
                        const float* __restrict__ Lu_bih, const float* __restrict__ Lu_bhh,
                        uint16_t* __restrict__ Wc, uint16_t* __restrict__ Wl,
                        float* __restrict__ bsc, float* __restrict__ bsl){
  int n = blockIdx.x;          // 0..511 (gate-major row, torch order i|f|g|o)
  int t = threadIdx.x;         // 0..127
  Wc[n*256 + t]       = f2bf(Cu_wih[n*128 + t]);
  Wc[n*256 + 128 + t] = f2bf(Cu_whh[n*128 + t]);
  Wl[n*384 + t]       = f2bf(Lu_wih[n*256 + t]);
  Wl[n*384 + 128 + t] = f2bf(Lu_wih[n*256 + 128 + t]);
  Wl[n*384 + 256 + t] = f2bf(Lu_whh[n*128 + t]);
  if (t == 0){
    bsc[n] = Cu_bih[n] + Cu_bhh[n];
    bsl[n] = Lu_bih[n] + Lu_bhh[n];
  }
}

// ---------------- MLP weights fp32 -> bf16 ----------------------------------
__global__ void k_cvtmsg(const float* __restrict__ LmW, const float* __restrict__ CmW,
                         uint16_t* __restrict__ LmWb, uint16_t* __restrict__ CmWb){
  int i = blockIdx.x*256 + threadIdx.x;       // 0 .. 2*49152
  if (i < 49152)            LmWb[i]         = f2bf(LmW[i]);
  else if (i < 2*49152)     CmWb[i - 49152] = f2bf(CmW[i - 49152]);
}

// ---------------- CSR build (both directions, one unified segment array) ----
__global__ void k_hist(const int* esrc, const int* edst, int* cnt){
  int e = blockIdx.x*256 + threadIdx.x; if (e >= NEDGE) return;
  int s = esrc[e], d = edst[e];
  if ((unsigned)d < (unsigned)NCLS) atomicAdd(&cnt[d], 1);
  if ((unsigned)s < (unsigned)NLIT) atomicAdd(&cnt[NCLS + s], 1);
}

__global__ void k_reduce(const int* cnt, int* part){
  __shared__ int sm[1024];
  int i = blockIdx.x*1024 + threadIdx.x;
  sm[threadIdx.x] = (i < NSEG) ? cnt[i] : 0;
  __syncthreads();
  for (int s = 512; s > 0; s >>= 1){
    if (threadIdx.x < s) sm[threadIdx.x] += sm[threadIdx.x + s];
    __syncthreads();
  }
  if (threadIdx.x == 0) part[blockIdx.x] = sm[0];
}

__global__ void k_scanpart(int* part, int nb){
  if (blockIdx.x == 0 && threadIdx.x == 0){
    int s = 0;
    for (int b = 0; b < nb; ++b){ int v = part[b]; part[b] = s; s += v; }
  }
}

__global__ void k_scanapply(const int* cnt, const int* part, int* off, int* cur){
  __shared__ int sm[1024];
  int i = blockIdx.x*1024 + threadIdx.x;
  int v = (i < NSEG) ? cnt[i] : 0;
  sm[threadIdx.x] = v;
  __syncthreads();
  for (int s = 1; s < 1024; s <<= 1){
    int t = (threadIdx.x >= s) ? sm[threadIdx.x - s] : 0;
    __syncthreads();
    sm[threadIdx.x] += t;
    __syncthreads();
  }
  if (i < NSEG){
    int excl = part[blockIdx.x] + sm[threadIdx.x] - v;
    off[i] = excl; cur[i] = excl;
    if (i == NSEG-1) off[NSEG] = excl + v;
  }
}

__global__ void k_scatter(const int* esrc, const int* edst, int* cur, int* csr){
  int e = blockIdx.x*256 + threadIdx.x; if (e >= NEDGE) return;
  int s = esrc[e], d = edst[e];
  if ((unsigned)s < (unsigned)NLIT && (unsigned)d < (unsigned)NCLS){
    int p  = atomicAdd(&cur[d], 1);        if ((unsigned)p  < (unsigned)CSRN) csr[p]  = s;
    int p2 = atomicAdd(&cur[NCLS + s], 1); if ((unsigned)p2 < (unsigned)CSRN) csr[p2] = d;
  }
}

// ---------------- segment sum: one wave per segment row (bf16 internal) -----
__global__ void k_segsum(const uint16_t* __restrict__ rows, int rowsN,
                         uint16_t* __restrict__ out,
                         const int* __restrict__ off, const int* __restrict__ csr,
                         int nseg, int segbase){
  int seg = blockIdx.x*4 + (threadIdx.x >> 6);
  if (seg >= nseg) return;
  int lane = threadIdx.x & 63;
  int s0 = off[segbase + seg], s1 = off[segbase + seg + 1];
  if (s0 < 0) s0 = 0;
  if (s1 > CSRN) s1 = CSRN;
  float ax = 0.f, ay = 0.f;
  for (int e = s0; e < s1; ++e){
    unsigned idx = (unsigned)csr[e];
    if (idx >= (unsigned)rowsN) idx = 0;     // defensive: wrong-but-finite
    uint32_t v = *reinterpret_cast<const uint32_t*>(rows + (size_t)idx*DD + lane*2);
    ax += bf2f((uint16_t)(v & 0xffffu));
    ay += bf2f((uint16_t)(v >> 16));
  }
  ax = sane(ax); ay = sane(ay);
  *reinterpret_cast<uint32_t*>(out + (size_t)seg*DD + lane*2) =
      (uint32_t)f2bf(ax) | ((uint32_t)f2bf(ay) << 16);
}

// ---------------- fused 3-layer MLP: out = L3(relu(L2(relu(L1(A))))) --------
// (unchanged from round 6 — verified WIN)
__global__ void __launch_bounds__(512, 4)
k_mlp3(const uint16_t* __restrict__ A, const uint16_t* __restrict__ W,
       const float* __restrict__ bias, uint16_t* __restrict__ out, int M){
  __shared__ uint16_t sX[8192];   // 16 KB: layer input
  __shared__ uint16_t sY[8192];   // 16 KB: layer output
  int tid  = threadIdx.x;
  int wv   = tid >> 6, lane = tid & 63;
  int mrow = lane & 15, qq = lane >> 4;
  int r0   = blockIdx.x*64;
  int slot = qq ^ ((mrow >> 1) & 3);     // swizzled read slot
  int j    = wv*16 + mrow;               // this thread's out-col (all layers)

  short8 bfr[3][4];
#pragma unroll
  for (int l = 0; l < 3; ++l)
#pragma unroll
    for (int kt = 0; kt < 4; ++kt)
      bfr[l][kt] = *reinterpret_cast<const short8*>(
          W + (size_t)l*16384 + (size_t)j*DD + kt*32 + qq*8);

#pragma unroll
  for (int p = 0; p < 2; ++p){
    int chunk = p*512 + tid;
    int kt  = chunk >> 8;
    int row = (chunk >> 2) & 63;
    int c   = chunk & 3;
    int qc  = c ^ ((row >> 1) & 3);
    long r  = r0 + row; if (r > M-1) r = M-1;        // tail clamp
    const uint16_t* src = A + (size_t)r*DD + kt*32 + qc*8;
    __builtin_amdgcn_global_load_lds((gvoid_t*)src,
                                     (svoid_t*)&sX[(size_t)(p*512 + wv*64)*8],
                                     16, 0, 0);
  }

  int ktj = j >> 5;                      // out-col's kstep (as next-layer k)
  int qcj = (j >> 3) & 3;                // out-col's chunk within kstep
  __syncthreads();                       // staging complete (vmcnt drained)

  uint16_t* sIn  = sX;
  uint16_t* sOut = sY;
#pragma unroll
  for (int l = 0; l < 3; ++l){
    float bv = bias[l*128 + j];
    floatx4 acc[4];
#pragma unroll
    for (int mi = 0; mi < 4; ++mi){ floatx4 z = {0.f,0.f,0.f,0.f}; acc[mi] = z; }
#pragma unroll
    for (int kt = 0; kt < 4; ++kt)
#pragma unroll
      for (int mi = 0; mi < 4; ++mi){
        short8 af = *reinterpret_cast<const short8*>(
            &sIn[(size_t)((kt*64 + mi*16 + mrow)*4 + slot)*8]);
        acc[mi] = __builtin_amdgcn_mfma_f32_16x16x32_bf16(af, bfr[l][kt], acc[mi], 0, 0, 0);
      }
    if (l < 2){
#pragma unroll
      for (int mi = 0; mi < 4; ++mi)
#pragma unroll
        for (int r2 = 0; r2 < 4; ++r2){
          int row = mi*16 + qq*4 + r2;
          float v = sane(acc[mi][r2] + bv);
          v = v > 0.f ? v : 0.f;                     // relu between layers
          int s = qcj ^ ((row >> 1) & 3);
          sOut[(size_t)((ktj*64 + row)*4 + s)*8 + (j & 7)] = f2bf(v);
        }
      __syncthreads();                   // sOut ready; sIn fully consumed
      uint16_t* t = sIn; sIn = sOut; sOut = t;
    } else {
#pragma unroll
      for (int mi = 0; mi < 4; ++mi)
#pragma unroll
        for (int r2 = 0; r2 < 4; ++r2){
          int row = r0 + mi*16 + qq*4 + r2;
          float v = sane(acc[mi][r2] + bv);
          if (row < M) out[(size_t)row*DD + j] = f2bf(v);
        }
    }
  }
}

// ---------------- clause LSTM: v5b LDS structure + counted-vmcnt sync -------
// REVERTED from R7's reg-B attempt (VGPR_Count=68 proved the compiler sank
// the 128-VGPR B-panel back into the loop -> v4 failure mode, 342 µs).
// This is the proven 180 µs structure (R5/R6).
// Block = 512 threads (8 waves), 64 rows x all 512 gate-cols.
// Wave fb owns feature cols [fb*16,+16) x 4 gates x 64 rows (16 frags).
// W staged per-K-step (32 KB) double-buffered; A slice (4 KB) staged by
// waves 0-3. XOR swizzle conflict-free; source inverse-swizzled for linear
// global_load_lds. Counted-vmcnt sync (wave-self-contained W staging);
// loop-final vmcnt(0)+barrier retires all A reads (incl. live hbC) before
// any epilogue write.
template<int K, int NEG1>
__global__ void __launch_bounds__(512, 4)
k_lstm_fused(const uint16_t* __restrict__ A0, const uint16_t* __restrict__ A1,
             const uint16_t* __restrict__ A2,
             const uint16_t* __restrict__ W, const float* __restrict__ bias,
             float* __restrict__ c32, uint16_t* __restrict__ hout, int M){
  constexpr int NT = K/32;                     // K-steps of 32
  __shared__ uint16_t sW[2][16384];            // [512 gate-rows][32 k], 64 KB
  __shared__ uint16_t sA[2][2048];             // [64 rows][32 k], 8 KB

  int tid  = threadIdx.x;
  int wv   = tid >> 6, lane = tid & 63;
  int mrow = lane & 15, qq = lane >> 4;
  int fb   = wv;                               // feature-16 block 0..7
  int r0   = blockIdx.x*64;
  int wvu  = __builtin_amdgcn_readfirstlane(wv);   // SGPR wave id (scalar branch)

  int slot = qq ^ ((mrow >> 1) & 3);           // swizzled read slot
  int sq   = (lane & 3) ^ ((lane >> 3) & 3);   // staging content chunk
  int srow = wv*16 + (lane >> 2);              // W stage row (mod 128)
  int alr  = (wv & 3)*16 + (lane >> 2);        // A stage local row (wv<4)

  floatx4 acc[4][4];                           // [mi][gg]
#pragma unroll
  for (int i = 0; i < 4; ++i)
#pragma unroll
    for (int j2 = 0; j2 < 4; ++j2){ floatx4 z = {0.f,0.f,0.f,0.f}; acc[i][j2] = z; }

  auto stage = [&](int buf, int tn){
    int kt = tn*32;
#pragma unroll
    for (int c = 0; c < 4; ++c){
      const uint16_t* src = W + (size_t)(srow + c*128)*K + kt + sq*8;
      __builtin_amdgcn_global_load_lds((gvoid_t*)src,
                                       (svoid_t*)&sW[buf][wv*512 + c*4096],
                                       16, 0, 0);
    }
    if (wvu < 4){
      int rg = tn >> 2;                        // region of this K-step
      const uint16_t* Ar = (rg == 0) ? A0 : ((rg == 1) ? A1 : A2);
      long gr = r0 + alr; if (gr > M-1) gr = M-1;           // tail clamp
      if (NEG1 && rg == 1) gr = (gr < NVARS) ? gr + NVARS : gr - NVARS;
      const uint16_t* asrc = Ar + (size_t)gr*DD + (tn & 3)*32 + sq*8;
      __builtin_amdgcn_global_load_lds((gvoid_t*)asrc,
                                       (svoid_t*)&sA[buf][wv*512],
                                       16, 0, 0);
    }
  };

  stage(0, 0);
  asm volatile("s_waitcnt vmcnt(0)" ::: "memory");
  __builtin_amdgcn_sched_barrier(0);
  __builtin_amdgcn_s_barrier();
  __builtin_amdgcn_sched_barrier(0);

#pragma unroll
  for (int t = 0; t < NT; ++t){
    const int cur = t & 1;
    if (t + 1 < NT){
      stage(cur ^ 1, t + 1);                   // prefetch stays in flight
      if (wvu < 4) asm volatile("s_waitcnt vmcnt(5)" ::: "memory");
      else         asm volatile("s_waitcnt vmcnt(4)" ::: "memory");
    } else {
      asm volatile("s_waitcnt vmcnt(0)" ::: "memory");
    }
    __builtin_amdgcn_sched_barrier(0);
    __builtin_amdgcn_s_barrier();              // all waves' stage(t) retired
    __builtin_amdgcn_sched_barrier(0);

    short8 af[4], bf[4];
#pragma unroll
    for (int mi = 0; mi < 4; ++mi)
      af[mi] = *reinterpret_cast<const short8*>(&sA[cur][(mi*16 + mrow)*32 + slot*8]);
#pragma unroll
    for (int gg = 0; gg < 4; ++gg)
      bf[gg] = *reinterpret_cast<const short8*>(&sW[cur][(gg*128 + fb*16 + mrow)*32 + slot*8]);
#pragma unroll
    for (int mi = 0; mi < 4; ++mi)
#pragma unroll
      for (int gg = 0; gg < 4; ++gg)
        acc[mi][gg] = __builtin_amdgcn_mfma_f32_16x16x32_bf16(af[mi], bf[gg], acc[mi][gg], 0, 0, 0);

    asm volatile("s_waitcnt lgkmcnt(0)" ::: "memory");
    __builtin_amdgcn_sched_barrier(0);
    __builtin_amdgcn_s_barrier();              // reads done before buf reuse
    __builtin_amdgcn_sched_barrier(0);
  }

  int j = fb*16 + mrow;                        // feature col in [0,128)
  float bi = bias[j], bfv = bias[j+128], bg = bias[j+256], bo = bias[j+384];
#pragma unroll
  for (int mi = 0; mi < 4; ++mi){
    floatx4 vi = acc[mi][0], vf = acc[mi][1], vg = acc[mi][2], vo = acc[mi][3];
#pragma unroll
    for (int r2 = 0; r2 < 4; ++r2){
      int row = r0 + mi*16 + qq*4 + r2;
      if (row < M){
        size_t ix = (size_t)row*DD + j;
        float iv = sane(vi[r2] + bi);
        float fv = sane(vf[r2] + bfv);
        float gv = sane(vg[r2] + bg);
        float ov = sane(vo[r2] + bo);
        float c0 = sane(c32[ix]);
        float c2 = sigm(fv)*c0 + sigm(iv)*tanh_f(gv);
        c32[ix]  = c2;
        hout[ix] = f2bf(sigm(ov)*tanh_f(c2));
      }
    }
  }
}

// ---------------- literal LSTM: v5b LDS pipeline + PAIRED rows --------------
// (unchanged from R7 — verified correct, snapshot-free)
// Block covers rows {b*32..+31} U {NVARS+b*32..+31}; negation is block-local
// -> live-hb reads are race-free under the loop-final vmcnt(0)+barrier.
__global__ void __launch_bounds__(512, 4)
k_lstm_lit(const uint16_t* __restrict__ A0, const uint16_t* __restrict__ hbl,
           const uint16_t* __restrict__ W, const float* __restrict__ bias,
           float* __restrict__ c32, uint16_t* __restrict__ hout){
  constexpr int NT = 12;                       // K=384
  __shared__ uint16_t sW[2][16384];            // [512 gate-rows][32 k], 64 KB
  __shared__ uint16_t sA[2][2048];             // [64 rows][32 k], 8 KB

  int tid  = threadIdx.x;
  int wv   = tid >> 6, lane = tid & 63;
  int mrow = lane & 15, qq = lane >> 4;
  int fb   = wv;
  long base = (long)blockIdx.x*32;
  int wvu  = __builtin_amdgcn_readfirstlane(wv);

  int slot = qq ^ ((mrow >> 1) & 3);           // swizzled read slot
  int sq   = (lane & 3) ^ ((lane >> 3) & 3);   // staging content chunk
  int srow = wv*16 + (lane >> 2);              // W stage row (mod 128)
  int alr  = (wv & 3)*16 + (lane >> 2);        // A stage local row (wv<4)

  auto pmap = [&](int lr)->long {
    long g = (lr < 32) ? base + lr : (long)NVARS + base + (lr - 32);
    long cap = (lr < 32) ? (long)NVARS - 1 : (long)NLIT - 1;
    return g > cap ? cap : g;
  };

  floatx4 acc[4][4];                           // [mi][gg]
#pragma unroll
  for (int i = 0; i < 4; ++i)
#pragma unroll
    for (int j2 = 0; j2 < 4; ++j2){ floatx4 z = {0.f,0.f,0.f,0.f}; acc[i][j2] = z; }

  auto stage = [&](int buf, int tn){
    int kt = tn*32;
#pragma unroll
    for (int c = 0; c < 4; ++c){
      const uint16_t* src = W + (size_t)(srow + c*128)*384 + kt + sq*8;
      __builtin_amdgcn_global_load_lds((gvoid_t*)src,
                                       (svoid_t*)&sW[buf][wv*512 + c*4096],
                                       16, 0, 0);
    }
    if (wvu < 4){
      int rg = tn >> 2;                        // 0 = l_msg, 1 = neg h, 2 = own h
      int lr = (rg == 1) ? ((alr + 32) & 63) : alr;
      long gr = pmap(lr);
      const uint16_t* Ar = (rg == 0) ? A0 : hbl;
      const uint16_t* asrc = Ar + (size_t)gr*DD + (tn & 3)*32 + sq*8;
      __builtin_amdgcn_global_load_lds((gvoid_t*)asrc,
                                       (svoid_t*)&sA[buf][wv*512],
                                       16, 0, 0);
    }
  };

  stage(0, 0);
  asm volatile("s_waitcnt vmcnt(0)" ::: "memory");
  __builtin_amdgcn_sched_barrier(0);
  __builtin_amdgcn_s_barrier();
  __builtin_amdgcn_sched_barrier(0);

#pragma unroll
  for (int t = 0; t < NT; ++t){
    const int cur = t & 1;
    if (t + 1 < NT){
      stage(cur ^ 1, t + 1);                   // prefetch stays in flight
      if (wvu < 4) asm volatile("s_waitcnt vmcnt(5)" ::: "memory");
      else         asm volatile("s_waitcnt vmcnt(4)" ::: "memory");
    } else {
      asm volatile("s_waitcnt vmcnt(0)" ::: "memory");
    }
    __builtin_amdgcn_sched_barrier(0);
    __builtin_amdgcn_s_barrier();              // all waves' stage(t) retired
    __builtin_amdgcn_sched_barrier(0);

    short8 af[4], bf[4];
#pragma unroll
    for (int mi = 0; mi < 4; ++mi)
      af[mi] = *reinterpret_cast<const short8*>(&sA[cur][(mi*16 + mrow)*32 + slot*8]);
#pragma unroll
    for (int gg = 0; gg < 4; ++gg)
      bf[gg] = *reinterpret_cast<const short8*>(&sW[cur][(gg*128 + fb*16 + mrow)*32 + slot*8]);
#pragma unroll
    for (int mi = 0; mi < 4; ++mi)
#pragma unroll
      for (int gg = 0; gg < 4; ++gg)
        acc[mi][gg] = __builtin_amdgcn_mfma_f32_16x16x32_bf16(af[mi], bf[gg], acc[mi][gg], 0, 0, 0);

    asm volatile("s_waitcnt lgkmcnt(0)" ::: "memory");
    __builtin_amdgcn_sched_barrier(0);
    __builtin_amdgcn_s_barrier();              // reads done before buf reuse
    __builtin_amdgcn_sched_barrier(0);
  }

  int j = fb*16 + mrow;
  float bi = bias[j], bfv = bias[j+128], bg = bias[j+256], bo = bias[j+384];
#pragma unroll
  for (int mi = 0; mi < 4; ++mi){
    floatx4 vi = acc[mi][0], vf = acc[mi][1], vg = acc[mi][2], vo = acc[mi][3];
#pragma unroll
    for (int r2 = 0; r2 < 4; ++r2){
      int lrow = mi*16 + qq*4 + r2;            // local row 0..63
      bool valid = (lrow < 32) ? (base + lrow < NVARS)
                               : (base + (lrow - 32) < NVARS);
      if (valid){
        long grow = (lrow < 32) ? base + lrow : (long)NVARS + base + (lrow - 32);
        size_t ix = (size_t)grow*DD + j;
        float iv = sane(vi[r2] + bi);
        float fv = sane(vf[r2] + bfv);
        float gv = sane(vg[r2] + bg);
        float ov = sane(vo[r2] + bo);
        float c0 = sane(c32[ix]);
        float c2 = sigm(fv)*c0 + sigm(iv)*tanh_f(gv);
        c32[ix]  = c2;
        hout[ix] = f2bf(sigm(ov)*tanh_f(c2));
      }
    }
  }
}

// ---------------- finalize: hb (bf16) -> d_out (fp32), overwrites c32 -------
__global__ void k_final(const uint16_t* __restrict__ hb, float* __restrict__ out){
  long i = (long)blockIdx.x*256 + threadIdx.x;   // units of 4 elements
  if (i >= (long)NNODE*DD/4) return;
  ushort4 v = *reinterpret_cast<const ushort4*>(hb + i*4);
  float4 o;
  o.x = bf2f(v.x); o.y = bf2f(v.y); o.z = bf2f(v.z); o.w = bf2f(v.w);
  *reinterpret_cast<float4*>(out + i*4) = o;
}

// ---------------------------------------------------------------------------
extern "C" void kernel_launch(void* const* d_in, const int* in_sizes, int n_in,
                              void* d_out, int out_size, void* d_ws, size_t ws_size,
                              hipStream_t stream){
  // FP32 float inputs (per reference: jax.random.normal -> float32)
  const float* Lw     = (const float*)d_in[0];
  const float* Lb     = (const float*)d_in[1];
  const float* Cw     = (const float*)d_in[2];
  const float* Cb     = (const float*)d_in[3];
  const float* LmW    = (const float*)d_in[4];    // [3,128,128]
  const float* LmB    = (const float*)d_in[5];    // [3,128] -> used directly as bias
  const float* CmW    = (const float*)d_in[6];
  const float* CmB    = (const float*)d_in[7];
  const float* Cu_wih = (const float*)d_in[8];    // [512,128]
  const float* Cu_whh = (const float*)d_in[9];
  const float* Cu_bih = (const float*)d_in[10];
  const float* Cu_bhh = (const float*)d_in[11];
  const float* Lu_wih = (const float*)d_in[12];   // [512,256]
  const float* Lu_whh = (const float*)d_in[13];   // [512,128]
  const float* Lu_bih = (const float*)d_in[14];
  const float* Lu_bhh = (const float*)d_in[15];
  const int* esrc = (const int*)d_in[16];
  const int* edst = (const int*)d_in[17];
  // d_in[18..20]: n_vars / n_clauses / num_rounds — fixed, hardcoded.

  // Workspace carve-up (~191 MB). fp32 c-state lives in d_out (153.6 MB),
  // which is dead scratch until k_final overwrites it with fp32 h.
  char* p = (char*)d_ws;
  auto alloc = [&](size_t bytes)->char* {
    char* r = p; p += (bytes + 255) & ~(size_t)255; return r;
  };
  int* cnt  = (int*)alloc((size_t)NSEG*4);
  int* off  = (int*)alloc((size_t)(NSEG+1)*4);
  int* cur  = (int*)alloc((size_t)NSEG*4);
  int nb = (NSEG + 1023) / 1024;                       // 293
  int* part = (int*)alloc((size_t)nb*4);
  int* csr  = (int*)alloc((size_t)CSRN*4);
  uint16_t* Wc   = (uint16_t*)alloc((size_t)512*256*2);
  uint16_t* Wl   = (uint16_t*)alloc((size_t)512*384*2);
  uint16_t* LmWb = (uint16_t*)alloc((size_t)3*128*128*2);
  uint16_t* CmWb = (uint16_t*)alloc((size_t)3*128*128*2);
  float* bsc = (float*)alloc(512*4);
  float* bsl = (float*)alloc(512*4);
  uint16_t* t0 = (uint16_t*)alloc((size_t)NCLS*DD*2);   // 51.2 MB
  uint16_t* t1 = (uint16_t*)alloc((size_t)NCLS*DD*2);   // 51.2 MB
  uint16_t* hb = (uint16_t*)alloc((size_t)NNODE*DD*2);  // 76.8 MB

  float* c32 = (float*)d_out;                    // fp32 c-state scratch in d_out
  uint16_t* hbC = hb  + (size_t)NLIT*DD;
  float*    cL  = c32;
  float*    cC  = c32 + (size_t)NLIT*DD;

  // ---- setup phase (ws re-poisoned every call: rebuild everything) ----
  hipMemsetAsync(cnt, 0, (size_t)NSEG*4, stream);
  k_init<<<(NNODE*DD + 255)/256, 256, 0, stream>>>(Lw, Lb, Cw, Cb, hb, c32);
  k_setup<<<512, 128, 0, stream>>>(Cu_wih, Cu_whh, Cu_bih, Cu_bhh,
                                   Lu_wih, Lu_whh, Lu_bih, Lu_bhh,
                                   Wc, Wl, bsc, bsl);
  k_cvtmsg<<<(2*49152 + 255)/256, 256, 0, stream>>>(LmW, CmW, LmWb, CmWb);
  k_hist<<<(NEDGE + 255)/256, 256, 0, stream>>>(esrc, edst, cnt);
  k_reduce<<<nb, 1024, 0, stream>>>(cnt, part);
  k_scanpart<<<1, 64, 0, stream>>>(part, nb);
  k_scanapply<<<nb, 1024, 0, stream>>>(cnt, part, off, cur);
  k_scatter<<<(NEDGE + 255)/256, 256, 0, stream>>>(esrc, edst, cur, csr);

  for (int rd = 0; rd < NROUNDS; ++rd){
    // literal message MLP (fused 3 layers): hb[0:NLIT] -> t0 (= lm)
    k_mlp3<<<1563, 512, 0, stream>>>(hb, LmWb, LmB, t0, NLIT);
    // clause inbox: c_msg[c] = sum lm[src]  -> t1
    k_segsum<<<50000, 256, 0, stream>>>(t0, NLIT, t1, off, csr, NCLS, 0);
    // clause LSTM (v5b LDS): A=[c_msg | live hbC], writes hbC,cC
    k_lstm_fused<256,0><<<3125, 512, 0, stream>>>(t1, hbC, nullptr, Wc, bsc, cC, hbC, NCLS);
    // clause message MLP (fused 3 layers): hbC -> t0 (= cm)
    k_mlp3<<<3125, 512, 0, stream>>>(hbC, CmWb, CmB, t0, NCLS);
    // literal inbox: l_msg[l] = sum cm[dst]  -> t1
    k_segsum<<<25000, 256, 0, stream>>>(t0, NCLS, t1, off, csr, NLIT, NCLS);
    // literal LSTM (paired rows, live hb, no snapshot): writes hb,cL
    k_lstm_lit<<<1563, 512, 0, stream>>>(t1, hb, Wl, bsl, cL, hb);
  }

  // final: convert bf16 h -> fp32 output (c-state in d_out is dead now)
  k_final<<<(NNODE*DD/4 + 255)/256, 256, 0, stream>>>(hb, (float*)d_out);
}